// Round 5
// baseline (294.818 us; speedup 1.0000x reference)
//
#include <hip/hip_runtime.h>
#include <math.h>

#define TPB 256
#define MAXDEG 8

static __device__ __forceinline__ void atomAddD(double* p, double v) {
  __hip_atomic_fetch_add(p, v, __ATOMIC_RELAXED, __HIP_MEMORY_SCOPE_AGENT);
}

static __device__ __forceinline__ double bredsum(double v) {
  __shared__ double sb[TPB];
  int t = threadIdx.x;
  sb[t] = v;
  __syncthreads();
  for (int o = TPB / 2; o > 0; o >>= 1) {
    if (t < o) sb[t] += sb[t + o];
    __syncthreads();
  }
  double r = sb[0];
  __syncthreads();
  return r;
}

// one Jacobi rotation, all indices compile-time -> stays in registers
template <int p, int q, int r>
static __device__ __forceinline__ void jrot(double A[3][3], double V[3][3]) {
  double apq = A[p][q];
  if (apq == 0.0) return;
  double app = A[p][p], aqq = A[q][q];
  double theta = (aqq - app) / (2.0 * apq);
  double t = 1.0 / (fabs(theta) + sqrt(theta * theta + 1.0));
  if (theta < 0.0) t = -t;
  double c = 1.0 / sqrt(t * t + 1.0), sn = t * c;
  A[p][p] = app - t * apq;
  A[q][q] = aqq + t * apq;
  A[p][q] = 0.0;
  A[q][p] = 0.0;
  double arp = A[r][p], arq = A[r][q];
  A[r][p] = c * arp - sn * arq; A[p][r] = A[r][p];
  A[r][q] = sn * arp + c * arq; A[q][r] = A[r][q];
#pragma unroll
  for (int k = 0; k < 3; k++) {
    double vkp = V[k][p], vkq = V[k][q];
    V[k][p] = c * vkp - sn * vkq;
    V[k][q] = sn * vkp + c * vkq;
  }
}

#define ESWAP(la, lax, lay, laz, lb, lbx, lby, lbz)                       \
  if (la < lb) {                                                          \
    double t_;                                                            \
    t_ = la; la = lb; lb = t_;                                            \
    t_ = lax; lax = lbx; lbx = t_;                                        \
    t_ = lay; lay = lby; lby = t_;                                        \
    t_ = laz; laz = lbz; lbz = t_;                                        \
  }

// Kabsch rotation via Jacobi eigen of S^T S; det-flip handled by
// R = v1 u1^T + v2 u2^T + (v1 x v2)(u1 x u2)^T   (all static indexing)
static __device__ void kabschR(const double S[3][3], double R9[9]) {
  double A[3][3];
#pragma unroll
  for (int a = 0; a < 3; a++)
#pragma unroll
    for (int c = 0; c < 3; c++)
      A[a][c] = S[0][a] * S[0][c] + S[1][a] * S[1][c] + S[2][a] * S[2][c];
  double V[3][3] = {{1, 0, 0}, {0, 1, 0}, {0, 0, 1}};
  for (int sw = 0; sw < 12; sw++) {
    double off = fabs(A[0][1]) + fabs(A[0][2]) + fabs(A[1][2]);
    double dia = fabs(A[0][0]) + fabs(A[1][1]) + fabs(A[2][2]);
    if (!(off > dia * 1e-15)) break;
    jrot<0, 1, 2>(A, V);
    jrot<0, 2, 1>(A, V);
    jrot<1, 2, 0>(A, V);
  }
  double l0 = A[0][0], l1 = A[1][1], l2 = A[2][2];
  double a0x = V[0][0], a0y = V[1][0], a0z = V[2][0];
  double a1x = V[0][1], a1y = V[1][1], a1z = V[2][1];
  double a2x = V[0][2], a2y = V[1][2], a2z = V[2][2];
  ESWAP(l0, a0x, a0y, a0z, l1, a1x, a1y, a1z);
  ESWAP(l0, a0x, a0y, a0z, l2, a2x, a2y, a2z);
  ESWAP(l1, a1x, a1y, a1z, l2, a2x, a2y, a2z);
  double R00 = 1, R01 = 0, R02 = 0, R10 = 0, R11 = 1, R12 = 0, R20 = 0, R21 = 0, R22 = 1;
  double b1x = S[0][0] * a0x + S[0][1] * a0y + S[0][2] * a0z;
  double b1y = S[1][0] * a0x + S[1][1] * a0y + S[1][2] * a0z;
  double b1z = S[2][0] * a0x + S[2][1] * a0y + S[2][2] * a0z;
  double b2x = S[0][0] * a1x + S[0][1] * a1y + S[0][2] * a1z;
  double b2y = S[1][0] * a1x + S[1][1] * a1y + S[1][2] * a1z;
  double b2z = S[2][0] * a1x + S[2][1] * a1y + S[2][2] * a1z;
  double n1 = sqrt(b1x * b1x + b1y * b1y + b1z * b1z);
  if (n1 > 1e-300 && isfinite(n1)) {
    double u1x = b1x / n1, u1y = b1y / n1, u1z = b1z / n1;
    double dp = u1x * b2x + u1y * b2y + u1z * b2z;
    b2x -= dp * u1x; b2y -= dp * u1y; b2z -= dp * u1z;
    double n2 = sqrt(b2x * b2x + b2y * b2y + b2z * b2z);
    double u2x, u2y, u2z;
    if (n2 > n1 * 1e-14) {
      u2x = b2x / n2; u2y = b2y / n2; u2z = b2z / n2;
    } else {
      double f0 = fabs(u1x), f1 = fabs(u1y), f2 = fabs(u1z);
      double e0, e1, e2;
      if (f0 <= f1 && f0 <= f2) { e0 = 1.0 - u1x * u1x; e1 = -u1x * u1y; e2 = -u1x * u1z; }
      else if (f1 <= f2)        { e0 = -u1y * u1x; e1 = 1.0 - u1y * u1y; e2 = -u1y * u1z; }
      else                      { e0 = -u1z * u1x; e1 = -u1z * u1y; e2 = 1.0 - u1z * u1z; }
      double nw = sqrt(e0 * e0 + e1 * e1 + e2 * e2);
      u2x = e0 / nw; u2y = e1 / nw; u2z = e2 / nw;
    }
    double u3x = u1y * u2z - u1z * u2y;
    double u3y = u1z * u2x - u1x * u2z;
    double u3z = u1x * u2y - u1y * u2x;
    double w3x = a0y * a1z - a0z * a1y;
    double w3y = a0z * a1x - a0x * a1z;
    double w3z = a0x * a1y - a0y * a1x;
    R00 = a0x * u1x + a1x * u2x + w3x * u3x;
    R01 = a0x * u1y + a1x * u2y + w3x * u3y;
    R02 = a0x * u1z + a1x * u2z + w3x * u3z;
    R10 = a0y * u1x + a1y * u2x + w3y * u3x;
    R11 = a0y * u1y + a1y * u2y + w3y * u3y;
    R12 = a0y * u1z + a1y * u2z + w3y * u3z;
    R20 = a0z * u1x + a1z * u2x + w3z * u3x;
    R21 = a0z * u1y + a1z * u2y + w3z * u3y;
    R22 = a0z * u1z + a1z * u2z + w3z * u3z;
  }
  R9[0] = R00; R9[1] = R01; R9[2] = R02;
  R9[3] = R10; R9[4] = R11; R9[5] = R12;
  R9[6] = R20; R9[7] = R21; R9[8] = R22;
}

static __device__ __forceinline__ double resid(const double* R, const double* es,
                                               const double* ec) {
  double r0 = ec[0] - (R[0] * es[0] + R[1] * es[1] + R[2] * es[2]);
  double r1 = ec[1] - (R[3] * es[0] + R[4] * es[1] + R[5] * es[2]);
  double r2 = ec[2] - (R[6] * es[0] + R[7] * es[1] + R[8] * es[2]);
  return r0 * r0 + r1 * r1 + r2 * r2;
}

static __device__ __forceinline__ void heronCots(double A2, double B2, double C2,
                                                 double* c0, double* c1, double* c2) {
  double A = sqrt(A2), Bl = sqrt(B2), C = sqrt(C2);
  double s = 0.5 * (A + Bl + C);
  double pr = s * (s - A) * (s - Bl) * (s - C);
  pr = pr < 1e-12 ? 1e-12 : pr;
  double inv4 = 1.0 / (4.0 * sqrt(pr));
  *c0 = (B2 + C2 - A2) * inv4;
  *c1 = (A2 + C2 - B2) * inv4;
  *c2 = (A2 + B2 - C2) * inv4;
}

// Fused: per-(b,f) face prep (areas into cdf, scr cots, std cots) +
//        per-f adjacency fill + per-e std edge-length sum.
__global__ void kPrep(const float* vscr, const float* vstd, const int* faces,
                      const int* edges, double* cdf, double* ccot, double* scot,
                      int* adjcnt, int4* adjtab, double* accEdgeStd,
                      int B, int Vn, int F, int E) {
  int i = blockIdx.x * TPB + threadIdx.x;
  if (i < B * F) {
    int b = i / F, f = i % F;
    const float* vb = vscr + (size_t)b * Vn * 3;
    int i0 = faces[f * 3], i1 = faces[f * 3 + 1], i2 = faces[f * 3 + 2];
    {
      double p0x = vb[i0 * 3], p0y = vb[i0 * 3 + 1], p0z = vb[i0 * 3 + 2];
      double p1x = vb[i1 * 3], p1y = vb[i1 * 3 + 1], p1z = vb[i1 * 3 + 2];
      double p2x = vb[i2 * 3], p2y = vb[i2 * 3 + 1], p2z = vb[i2 * 3 + 2];
      double ax = p1x - p0x, ay = p1y - p0y, az = p1z - p0z;
      double bx = p2x - p0x, by = p2y - p0y, bz = p2z - p0z;
      double cx = ay * bz - az * by, cy = az * bx - ax * bz, cz = ax * by - ay * bx;
      cdf[i] = 0.5 * sqrt(cx * cx + cy * cy + cz * cz);
      double dx = p1x - p2x, dy = p1y - p2y, dz = p1z - p2z;
      double A2 = dx * dx + dy * dy + dz * dz;
      double B2 = bx * bx + by * by + bz * bz;
      double C2 = ax * ax + ay * ay + az * az;
      double c0, c1, c2;
      heronCots(A2, B2, C2, &c0, &c1, &c2);
      ccot[(size_t)i * 3 + 0] = c0;
      ccot[(size_t)i * 3 + 1] = c1;
      ccot[(size_t)i * 3 + 2] = c2;
    }
    if (b == 0) {
      double p0x = vstd[i0 * 3], p0y = vstd[i0 * 3 + 1], p0z = vstd[i0 * 3 + 2];
      double p1x = vstd[i1 * 3], p1y = vstd[i1 * 3 + 1], p1z = vstd[i1 * 3 + 2];
      double p2x = vstd[i2 * 3], p2y = vstd[i2 * 3 + 1], p2z = vstd[i2 * 3 + 2];
      double ax = p1x - p0x, ay = p1y - p0y, az = p1z - p0z;
      double bx = p2x - p0x, by = p2y - p0y, bz = p2z - p0z;
      double dx = p1x - p2x, dy = p1y - p2y, dz = p1z - p2z;
      double A2 = dx * dx + dy * dy + dz * dz;
      double B2 = bx * bx + by * by + bz * bz;
      double C2 = ax * ax + ay * ay + az * az;
      double c0, c1, c2;
      heronCots(A2, B2, C2, &c0, &c1, &c2);
      scot[(size_t)f * 3 + 0] = c0;
      scot[(size_t)f * 3 + 1] = c1;
      scot[(size_t)f * 3 + 2] = c2;
      // adjacency fill (faces are batch-invariant)
      int f3 = f * 3;
      int s0 = atomicAdd(&adjcnt[i0], 1);
      if (s0 < MAXDEG) adjtab[(size_t)i0 * MAXDEG + s0] = make_int4(i1, i2, f3 + 1, f3 + 2);
      int s1 = atomicAdd(&adjcnt[i1], 1);
      if (s1 < MAXDEG) adjtab[(size_t)i1 * MAXDEG + s1] = make_int4(i2, i0, f3 + 2, f3 + 0);
      int s2 = atomicAdd(&adjcnt[i2], 1);
      if (s2 < MAXDEG) adjtab[(size_t)i2 * MAXDEG + s2] = make_int4(i0, i1, f3 + 0, f3 + 1);
    }
  }
  double eval = 0.0;
  if (i < E) {
    int e0 = edges[(size_t)i * 2], e1 = edges[(size_t)i * 2 + 1];
    double dx = (double)vstd[e0 * 3 + 0] - vstd[e1 * 3 + 0];
    double dy = (double)vstd[e0 * 3 + 1] - vstd[e1 * 3 + 1];
    double dz = (double)vstd[e0 * 3 + 2] - vstd[e1 * 3 + 2];
    eval = sqrt(dx * dx + dy * dy + dz * dz);
  }
  double r = bredsum(eval);
  if (threadIdx.x == 0) atomAddD(accEdgeStd, r);
}

// Single-pass scan: per-chunk inclusive scan (wave shuffles) + chunk sums;
// last-finishing block computes per-batch exclusive chunk offsets.
__global__ void kScanFused(double* a, double* bsum, double* boffs, int F, int nc,
                           int B, int* cnt) {
  int blk = blockIdx.x;
  int b = blk / nc, c = blk % nc;
  int t = threadIdx.x, lane = t & 63, wid = t >> 6;
  int f = c * 1024 + t;
  size_t idx = (size_t)b * F + f;
  double v = (f < F) ? a[idx] : 0.0;
  double x = v;
#pragma unroll
  for (int o = 1; o < 64; o <<= 1) {
    double y = __shfl_up(x, o, 64);
    if (lane >= o) x += y;
  }
  __shared__ double wsum[16];
  __shared__ double woffs[16];
  if (lane == 63) wsum[wid] = x;
  __syncthreads();
  if (wid == 0) {
    double s = (lane < 16) ? wsum[lane] : 0.0;
    double xs = s;
#pragma unroll
    for (int o = 1; o < 16; o <<= 1) {
      double y = __shfl_up(xs, o, 64);
      if (lane >= o) xs += y;
    }
    double ex = __shfl_up(xs, 1, 64);
    if (lane < 16) woffs[lane] = (lane == 0) ? 0.0 : ex;
  }
  __syncthreads();
  x += woffs[wid];
  if (f < F) a[idx] = x;
  if (t == 1023) bsum[(size_t)b * nc + c] = x;
  __threadfence();
  __shared__ int amlast;
  if (t == 0) {
    int old = __hip_atomic_fetch_add(cnt, 1, __ATOMIC_ACQ_REL, __HIP_MEMORY_SCOPE_AGENT);
    amlast = (old == (int)gridDim.x - 1) ? 1 : 0;
  }
  __syncthreads();
  if (amlast && wid == 0) {
    for (int bb = 0; bb < B; bb++) {
      double carry = 0.0;
      for (int base = 0; base < nc; base += 64) {
        int cc = base + lane;
        double s = (cc < nc) ? bsum[(size_t)bb * nc + cc] : 0.0;
        double xs = s;
#pragma unroll
        for (int o = 1; o < 64; o <<= 1) {
          double y = __shfl_up(xs, o, 64);
          if (lane >= o) xs += y;
        }
        double ex = __shfl_up(xs, 1, 64);
        double excl = (lane == 0) ? 0.0 : ex;
        if (cc < nc) boffs[(size_t)bb * nc + cc] = carry + excl;
        carry += __shfl(xs, 63, 64);
      }
    }
  }
}

// two-level binary search: chunk offsets (boffs/bsum), then in-chunk scan
__global__ void kSample(const float* verts, const int* faces, const double* cdf,
                        const double* bsum, const double* boffs,
                        const float* rfu, const float* rbary, float* samples,
                        int B, int Vn, int F, int S, int nc) {
  int i = blockIdx.x * blockDim.x + threadIdx.x;
  if (i >= B * S) return;
  int b = i / S;
  const double* bo = boffs + (size_t)b * nc;
  const double* bs = bsum + (size_t)b * nc;
  double total = bo[nc - 1] + bs[nc - 1];
  double tgt = (double)rfu[i] * total;
  int lo = 0, hi = nc;  // first chunk with inclusive prefix >= tgt
  while (lo < hi) {
    int m = (lo + hi) >> 1;
    if (bo[m] + bs[m] < tgt) lo = m + 1; else hi = m;
  }
  int c = lo < nc ? lo : nc - 1;
  double thr = tgt - bo[c];
  const double* cc = cdf + (size_t)b * F + (size_t)c * 1024;
  int lim = F - c * 1024; if (lim > 1024) lim = 1024;
  lo = 0; hi = lim;
  while (lo < hi) {
    int m = (lo + hi) >> 1;
    if (cc[m] < thr) lo = m + 1; else hi = m;
  }
  int j = lo < lim ? lo : lim - 1;
  int f = c * 1024 + j;
  const float* vb = verts + (size_t)b * Vn * 3;
  int i0 = faces[f * 3], i1 = faces[f * 3 + 1], i2 = faces[f * 3 + 2];
  float r0 = rbary[(size_t)i * 2], r1 = rbary[(size_t)i * 2 + 1];
  float su = sqrtf(r0);
  float w0 = 1.f - su, w1 = su * (1.f - r1), w2 = su * r1;
  samples[(size_t)i * 3 + 0] = w0 * vb[i0 * 3 + 0] + w1 * vb[i1 * 3 + 0] + w2 * vb[i2 * 3 + 0];
  samples[(size_t)i * 3 + 1] = w0 * vb[i0 * 3 + 1] + w1 * vb[i1 * 3 + 1] + w2 * vb[i2 * 3 + 1];
  samples[(size_t)i * 3 + 2] = w0 * vb[i0 * 3 + 2] + w1 * vb[i1 * 3 + 2] + w2 * vb[i2 * 3 + 2];
}

// both chamfer directions in one launch: z = dir*B + b
__global__ void kChamferBoth(const float* smp, const float* trg, unsigned* rowmin,
                             int B, int S) {
  int z = blockIdx.z;
  int dir = z / B, b = z % B;
  const float* X = dir ? trg : smp;
  const float* Y = dir ? smp : trg;
  int i = blockIdx.x * TPB + threadIdx.x;
  int j0 = blockIdx.y * TPB;
  int n = min(TPB, S - j0);
  __shared__ float4 sy[TPB];
  const float* Yb = Y + ((size_t)b * S + j0) * 3;
  if ((int)threadIdx.x < n) {
    int t = threadIdx.x;
    sy[t] = make_float4(Yb[t * 3], Yb[t * 3 + 1], Yb[t * 3 + 2], 0.f);
  }
  __syncthreads();
  if (i >= S) return;
  const float* Xb = X + (size_t)b * S * 3;
  float x0 = Xb[i * 3], x1 = Xb[i * 3 + 1], x2 = Xb[i * 3 + 2];
  float inf = __int_as_float(0x7f800000);
  float m0 = inf, m1 = inf, m2 = inf, m3 = inf;
  int k = 0;
  for (; k + 4 <= n; k += 4) {
    float4 y0 = sy[k], y1 = sy[k + 1], y2 = sy[k + 2], y3 = sy[k + 3];
    float a0 = x0 - y0.x, b0 = x1 - y0.y, c0 = x2 - y0.z;
    float a1 = x0 - y1.x, b1 = x1 - y1.y, c1 = x2 - y1.z;
    float a2 = x0 - y2.x, b2 = x1 - y2.y, c2 = x2 - y2.z;
    float a3 = x0 - y3.x, b3 = x1 - y3.y, c3 = x2 - y3.z;
    m0 = fminf(m0, a0 * a0 + b0 * b0 + c0 * c0);
    m1 = fminf(m1, a1 * a1 + b1 * b1 + c1 * c1);
    m2 = fminf(m2, a2 * a2 + b2 * b2 + c2 * c2);
    m3 = fminf(m3, a3 * a3 + b3 * b3 + c3 * c3);
  }
  for (; k < n; k++) {
    float4 y = sy[k];
    float a = x0 - y.x, bb = x1 - y.y, cc = x2 - y.z;
    m0 = fminf(m0, a * a + bb * bb + cc * cc);
  }
  float mn = fminf(fminf(m0, m1), fminf(m2, m3));
  atomicMin(&rowmin[((size_t)dir * B + b) * S + i], __float_as_uint(mn));
}

// fused: rowmin reduction + scr edge loss
__global__ void kMisc(const unsigned* rm, int nrm, const float* vscr, const int* edges,
                      int B, int Vn, int E, const double* tacc,
                      double* accCh, double* accEd) {
  int i = blockIdx.x * TPB + threadIdx.x;
  double v = 0.0;
  if (i < nrm) v = (double)__uint_as_float(rm[i]);
  double r = bredsum(v);
  if (threadIdx.x == 0) atomAddD(accCh, r);
  double tl = tacc[0] / (double)E;
  double val = 0.0;
  if (i < B * E) {
    int b = i / E, e = i % E;
    const float* vb = vscr + (size_t)b * Vn * 3;
    int e0 = edges[(size_t)e * 2], e1 = edges[(size_t)e * 2 + 1];
    double dx = (double)vb[e0 * 3 + 0] - vb[e1 * 3 + 0];
    double dy = (double)vb[e0 * 3 + 1] - vb[e1 * 3 + 1];
    double dz = (double)vb[e0 * 3 + 2] - vb[e1 * 3 + 2];
    double l = sqrt(dx * dx + dy * dy + dz * dz);
    double d = l - tl;
    val = d * d;
  }
  double r2 = bredsum(val);
  if (threadIdx.x == 0) atomAddD(accEd, r2);
}

// ---- per-vertex: Laplacian norm + ARAP S accumulate + Kabsch R ----
__global__ void kVertexLapR(const float* vstd, const float* vscr,
                            const int* cnt, const int4* adjtab, const double* scot,
                            const double* ccot, double* Rmat, int B, int Vn, int F,
                            double* accLap) {
  int idx = blockIdx.x * TPB + threadIdx.x;
  double vlap = 0.0;
  if (idx < B * Vn) {
    int b = idx / Vn, v = idx % Vn;
    const float* cb = vscr + (size_t)b * Vn * 3;
    const double* ccb = ccot + (size_t)b * F * 3;
    double pasx = vstd[v * 3], pasy = vstd[v * 3 + 1], pasz = vstd[v * 3 + 2];
    double pacx = cb[v * 3], pacy = cb[v * 3 + 1], pacz = cb[v * 3 + 2];
    int n = cnt[v];
    if (n > MAXDEG) n = MAXDEG;
    const int4* at = adjtab + (size_t)v * MAXDEG;
    double S00 = 0, S01 = 0, S02 = 0, S10 = 0, S11 = 0, S12 = 0, S20 = 0, S21 = 0, S22 = 0;
    double Lx = 0, Ly = 0, Lz = 0, rw = 0;
    for (int k = 0; k < n; k++) {
      int4 e = at[k];
      int jb = e.x, jc = e.y;
      double cBs = scot[e.z], cCs = scot[e.w];
      double cBc = ccb[e.z], cCc = ccb[e.w];
      double pbsx = vstd[jb * 3], pbsy = vstd[jb * 3 + 1], pbsz = vstd[jb * 3 + 2];
      double pcsx = vstd[jc * 3], pcsy = vstd[jc * 3 + 1], pcsz = vstd[jc * 3 + 2];
      double pbcx = cb[jb * 3], pbcy = cb[jb * 3 + 1], pbcz = cb[jb * 3 + 2];
      double pccx = cb[jc * 3], pccy = cb[jc * 3 + 1], pccz = cb[jc * 3 + 2];
      Lx += cCc * pbcx + cBc * pccx;
      Ly += cCc * pbcy + cBc * pccy;
      Lz += cCc * pbcz + cBc * pccz;
      rw += cBc + cCc;
      double e1sx = pasx - pbsx, e1sy = pasy - pbsy, e1sz = pasz - pbsz;
      double e2sx = pasx - pcsx, e2sy = pasy - pcsy, e2sz = pasz - pcsz;
      double e1cx = pacx - pbcx, e1cy = pacy - pbcy, e1cz = pacz - pbcz;
      double e2cx = pacx - pccx, e2cy = pacy - pccy, e2cz = pacz - pccz;
      S00 += cCs * e1sx * e1cx + cBs * e2sx * e2cx;
      S01 += cCs * e1sx * e1cy + cBs * e2sx * e2cy;
      S02 += cCs * e1sx * e1cz + cBs * e2sx * e2cz;
      S10 += cCs * e1sy * e1cx + cBs * e2sy * e2cx;
      S11 += cCs * e1sy * e1cy + cBs * e2sy * e2cy;
      S12 += cCs * e1sy * e1cz + cBs * e2sy * e2cz;
      S20 += cCs * e1sz * e1cx + cBs * e2sz * e2cx;
      S21 += cCs * e1sz * e1cy + cBs * e2sz * e2cy;
      S22 += cCs * e1sz * e1cz + cBs * e2sz * e2cz;
    }
    double inv = (rw > 0.0) ? 1.0 / fmax(rw, 1e-12) : 0.0;
    double dx = Lx * inv - pacx, dy = Ly * inv - pacy, dz = Lz * inv - pacz;
    vlap = sqrt(dx * dx + dy * dy + dz * dz);
    double S[3][3] = {{S00, S01, S02}, {S10, S11, S12}, {S20, S21, S22}};
    double R9[9];
    kabschR(S, R9);
    double* rp = Rmat + (size_t)idx * 9;
#pragma unroll
    for (int r = 0; r < 9; r++) rp[r] = R9[r];
  }
  double r1 = bredsum(vlap);
  if (threadIdx.x == 0) atomAddD(accLap, r1);
}

// per-(b,face) rigid residual + last-block finalize
__global__ void kRigidResFin(const float* vstd, const float* vscr, const int* faces,
                             const double* scot, const double* Rmat, int B, int Vn,
                             int F, double* accum, int* cnt, float* out, int S, int E) {
  int i = blockIdx.x * TPB + threadIdx.x;
  double val = 0.0;
  if (i < B * F) {
    int b = i / F, f = i % F;
    int i0 = faces[f * 3], i1 = faces[f * 3 + 1], i2 = faces[f * 3 + 2];
    const float* cb = vscr + (size_t)b * Vn * 3;
    double cs0 = scot[(size_t)f * 3], cs1 = scot[(size_t)f * 3 + 1], cs2 = scot[(size_t)f * 3 + 2];
    double p0x = vstd[i0 * 3], p0y = vstd[i0 * 3 + 1], p0z = vstd[i0 * 3 + 2];
    double p1x = vstd[i1 * 3], p1y = vstd[i1 * 3 + 1], p1z = vstd[i1 * 3 + 2];
    double p2x = vstd[i2 * 3], p2y = vstd[i2 * 3 + 1], p2z = vstd[i2 * 3 + 2];
    double q0x = cb[i0 * 3], q0y = cb[i0 * 3 + 1], q0z = cb[i0 * 3 + 2];
    double q1x = cb[i1 * 3], q1y = cb[i1 * 3 + 1], q1z = cb[i1 * 3 + 2];
    double q2x = cb[i2 * 3], q2y = cb[i2 * 3 + 1], q2z = cb[i2 * 3 + 2];
    double e01s[3] = {p0x - p1x, p0y - p1y, p0z - p1z};
    double e02s[3] = {p0x - p2x, p0y - p2y, p0z - p2z};
    double e12s[3] = {p1x - p2x, p1y - p2y, p1z - p2z};
    double e01c[3] = {q0x - q1x, q0y - q1y, q0z - q1z};
    double e02c[3] = {q0x - q2x, q0y - q2y, q0z - q2z};
    double e12c[3] = {q1x - q2x, q1y - q2y, q1z - q2z};
    const double* R0 = Rmat + ((size_t)b * Vn + i0) * 9;
    const double* R1 = Rmat + ((size_t)b * Vn + i1) * 9;
    const double* R2 = Rmat + ((size_t)b * Vn + i2) * 9;
    val = cs1 * resid(R0, e02s, e02c) + cs2 * resid(R0, e01s, e01c)
        + cs0 * resid(R1, e12s, e12c) + cs2 * resid(R1, e01s, e01c)
        + cs1 * resid(R2, e02s, e02c) + cs0 * resid(R2, e12s, e12c);
  }
  double r = bredsum(val);
  if (threadIdx.x == 0) atomAddD(accum + 4, r);
  __threadfence();
  __shared__ int amlast;
  if (threadIdx.x == 0) {
    int old = __hip_atomic_fetch_add(cnt, 1, __ATOMIC_ACQ_REL, __HIP_MEMORY_SCOPE_AGENT);
    amlast = (old == (int)gridDim.x - 1) ? 1 : 0;
  }
  __syncthreads();
  if (amlast && threadIdx.x == 0) {
    out[0] = (float)(accum[0] / ((double)B * S));
    out[1] = 1e-5f;
    out[2] = (float)(accum[1] / ((double)B * Vn));
    out[3] = (float)(accum[3] / ((double)B * E));
    out[4] = (float)(accum[4] / ((double)B * Vn));
  }
}

extern "C" void kernel_launch(void* const* d_in, const int* in_sizes, int n_in,
                              void* d_out, int out_size, void* d_ws, size_t ws_size,
                              hipStream_t stream) {
  const float* vscr = (const float*)d_in[0];
  const float* vstd = (const float*)d_in[1];
  const float* trg  = (const float*)d_in[2];
  const float* rfu  = (const float*)d_in[3];
  const float* rby  = (const float*)d_in[4];
  const int* faces  = (const int*)d_in[5];
  const int* edges  = (const int*)d_in[6];
  float* out = (float*)d_out;

  int nVs = in_sizes[1];
  int Vn = nVs / 3;
  int B = in_sizes[0] / nVs;
  int S = in_sizes[3] / B;
  int F = in_sizes[5] / 3;
  int E = in_sizes[6] / 2;
  int nc = (F + 1023) / 1024;

  char* p = (char*)d_ws;
  auto alloc = [&](size_t bytes) -> void* {
    void* r = (void*)p;
    p += (bytes + 255) & ~(size_t)255;
    return r;
  };
  double* cdf   = (double*)alloc((size_t)B * F * sizeof(double));
  double* bsum  = (double*)alloc((size_t)B * nc * sizeof(double));
  double* boffs = (double*)alloc((size_t)B * nc * sizeof(double));
  double* scot  = (double*)alloc((size_t)F * 3 * sizeof(double));
  double* ccot  = (double*)alloc((size_t)B * F * 3 * sizeof(double));
  double* Rmat  = (double*)alloc((size_t)B * Vn * 9 * sizeof(double));
  float* samples   = (float*)alloc((size_t)B * S * 3 * sizeof(float));
  unsigned* rowmin = (unsigned*)alloc((size_t)2 * B * S * sizeof(unsigned));
  int4* adjtab  = (int4*)alloc((size_t)Vn * MAXDEG * sizeof(int4));
  // zeroed region: adjcnt[Vn] | counters[8 ints] | accum[8 doubles]
  size_t zbytes = (size_t)Vn * sizeof(int) + 8 * sizeof(int) + 8 * sizeof(double);
  char* zbase   = (char*)alloc(zbytes);
  int* adjcnt   = (int*)zbase;
  int* cnts     = (int*)(zbase + (size_t)Vn * sizeof(int));  // [0]=scan, [1]=fin
  double* accum = (double*)(zbase + (size_t)Vn * sizeof(int) + 8 * sizeof(int));
  // accum: [0]=chamfer, [1]=lap, [2]=target_len, [3]=edge, [4]=rigid

  hipMemsetAsync(zbase, 0, zbytes, stream);
  int nrm = 2 * B * S;
  hipMemsetAsync(rowmin, 0xFF, (size_t)nrm * sizeof(unsigned), stream);

  int BF = B * F;
  kPrep<<<(BF + TPB - 1) / TPB, TPB, 0, stream>>>(vscr, vstd, faces, edges, cdf, ccot,
                                                  scot, adjcnt, adjtab, accum + 2,
                                                  B, Vn, F, E);
  kScanFused<<<B * nc, 1024, 0, stream>>>(cdf, bsum, boffs, F, nc, B, cnts + 0);
  kSample<<<(B * S + TPB - 1) / TPB, TPB, 0, stream>>>(vscr, faces, cdf, bsum, boffs,
                                                       rfu, rby, samples, B, Vn, F, S, nc);
  kVertexLapR<<<(B * Vn + TPB - 1) / TPB, TPB, 0, stream>>>(vstd, vscr, adjcnt, adjtab,
                                                            scot, ccot, Rmat, B, Vn, F,
                                                            accum + 1);
  dim3 cg((S + TPB - 1) / TPB, (S + TPB - 1) / TPB, 2 * B);
  kChamferBoth<<<cg, TPB, 0, stream>>>(samples, trg, rowmin, B, S);
  int nmisc = nrm > B * E ? nrm : B * E;
  kMisc<<<(nmisc + TPB - 1) / TPB, TPB, 0, stream>>>(rowmin, nrm, vscr, edges, B, Vn, E,
                                                     accum + 2, accum + 0, accum + 3);
  kRigidResFin<<<(BF + TPB - 1) / TPB, TPB, 0, stream>>>(vstd, vscr, faces, scot, Rmat,
                                                         B, Vn, F, accum, cnts + 1,
                                                         out, S, E);
}

// Round 6
// 197.412 us; speedup vs baseline: 1.4934x; 1.4934x over previous
//
#include <hip/hip_runtime.h>
#include <math.h>

#define TPB 256
#define MAXDEG 8

static __device__ __forceinline__ void atomAddD(double* p, double v) {
  __hip_atomic_fetch_add(p, v, __ATOMIC_RELAXED, __HIP_MEMORY_SCOPE_AGENT);
}

static __device__ __forceinline__ double bredsum(double v) {
  __shared__ double sb[TPB];
  int t = threadIdx.x;
  sb[t] = v;
  __syncthreads();
  for (int o = TPB / 2; o > 0; o >>= 1) {
    if (t < o) sb[t] += sb[t + o];
    __syncthreads();
  }
  double r = sb[0];
  __syncthreads();
  return r;
}

// one Jacobi rotation, all indices compile-time -> stays in registers
template <int p, int q, int r>
static __device__ __forceinline__ void jrot(double A[3][3], double V[3][3]) {
  double apq = A[p][q];
  if (apq == 0.0) return;
  double app = A[p][p], aqq = A[q][q];
  double theta = (aqq - app) / (2.0 * apq);
  double t = 1.0 / (fabs(theta) + sqrt(theta * theta + 1.0));
  if (theta < 0.0) t = -t;
  double c = 1.0 / sqrt(t * t + 1.0), sn = t * c;
  A[p][p] = app - t * apq;
  A[q][q] = aqq + t * apq;
  A[p][q] = 0.0;
  A[q][p] = 0.0;
  double arp = A[r][p], arq = A[r][q];
  A[r][p] = c * arp - sn * arq; A[p][r] = A[r][p];
  A[r][q] = sn * arp + c * arq; A[q][r] = A[r][q];
#pragma unroll
  for (int k = 0; k < 3; k++) {
    double vkp = V[k][p], vkq = V[k][q];
    V[k][p] = c * vkp - sn * vkq;
    V[k][q] = sn * vkp + c * vkq;
  }
}

#define ESWAP(la, lax, lay, laz, lb, lbx, lby, lbz)                       \
  if (la < lb) {                                                          \
    double t_;                                                            \
    t_ = la; la = lb; lb = t_;                                            \
    t_ = lax; lax = lbx; lbx = t_;                                        \
    t_ = lay; lay = lby; lby = t_;                                        \
    t_ = laz; laz = lbz; lbz = t_;                                        \
  }

// Kabsch rotation via Jacobi eigen of S^T S; det-flip handled by
// R = v1 u1^T + v2 u2^T + (v1 x v2)(u1 x u2)^T   (all static indexing)
static __device__ void kabschR(const double S[3][3], double R9[9]) {
  double A[3][3];
#pragma unroll
  for (int a = 0; a < 3; a++)
#pragma unroll
    for (int c = 0; c < 3; c++)
      A[a][c] = S[0][a] * S[0][c] + S[1][a] * S[1][c] + S[2][a] * S[2][c];
  double V[3][3] = {{1, 0, 0}, {0, 1, 0}, {0, 0, 1}};
  for (int sw = 0; sw < 12; sw++) {
    double off = fabs(A[0][1]) + fabs(A[0][2]) + fabs(A[1][2]);
    double dia = fabs(A[0][0]) + fabs(A[1][1]) + fabs(A[2][2]);
    if (!(off > dia * 1e-15)) break;
    jrot<0, 1, 2>(A, V);
    jrot<0, 2, 1>(A, V);
    jrot<1, 2, 0>(A, V);
  }
  double l0 = A[0][0], l1 = A[1][1], l2 = A[2][2];
  double a0x = V[0][0], a0y = V[1][0], a0z = V[2][0];
  double a1x = V[0][1], a1y = V[1][1], a1z = V[2][1];
  double a2x = V[0][2], a2y = V[1][2], a2z = V[2][2];
  ESWAP(l0, a0x, a0y, a0z, l1, a1x, a1y, a1z);
  ESWAP(l0, a0x, a0y, a0z, l2, a2x, a2y, a2z);
  ESWAP(l1, a1x, a1y, a1z, l2, a2x, a2y, a2z);
  double R00 = 1, R01 = 0, R02 = 0, R10 = 0, R11 = 1, R12 = 0, R20 = 0, R21 = 0, R22 = 1;
  double b1x = S[0][0] * a0x + S[0][1] * a0y + S[0][2] * a0z;
  double b1y = S[1][0] * a0x + S[1][1] * a0y + S[1][2] * a0z;
  double b1z = S[2][0] * a0x + S[2][1] * a0y + S[2][2] * a0z;
  double b2x = S[0][0] * a1x + S[0][1] * a1y + S[0][2] * a1z;
  double b2y = S[1][0] * a1x + S[1][1] * a1y + S[1][2] * a1z;
  double b2z = S[2][0] * a1x + S[2][1] * a1y + S[2][2] * a1z;
  double n1 = sqrt(b1x * b1x + b1y * b1y + b1z * b1z);
  if (n1 > 1e-300 && isfinite(n1)) {
    double u1x = b1x / n1, u1y = b1y / n1, u1z = b1z / n1;
    double dp = u1x * b2x + u1y * b2y + u1z * b2z;
    b2x -= dp * u1x; b2y -= dp * u1y; b2z -= dp * u1z;
    double n2 = sqrt(b2x * b2x + b2y * b2y + b2z * b2z);
    double u2x, u2y, u2z;
    if (n2 > n1 * 1e-14) {
      u2x = b2x / n2; u2y = b2y / n2; u2z = b2z / n2;
    } else {
      double f0 = fabs(u1x), f1 = fabs(u1y), f2 = fabs(u1z);
      double e0, e1, e2;
      if (f0 <= f1 && f0 <= f2) { e0 = 1.0 - u1x * u1x; e1 = -u1x * u1y; e2 = -u1x * u1z; }
      else if (f1 <= f2)        { e0 = -u1y * u1x; e1 = 1.0 - u1y * u1y; e2 = -u1y * u1z; }
      else                      { e0 = -u1z * u1x; e1 = -u1z * u1y; e2 = 1.0 - u1z * u1z; }
      double nw = sqrt(e0 * e0 + e1 * e1 + e2 * e2);
      u2x = e0 / nw; u2y = e1 / nw; u2z = e2 / nw;
    }
    double u3x = u1y * u2z - u1z * u2y;
    double u3y = u1z * u2x - u1x * u2z;
    double u3z = u1x * u2y - u1y * u2x;
    double w3x = a0y * a1z - a0z * a1y;
    double w3y = a0z * a1x - a0x * a1z;
    double w3z = a0x * a1y - a0y * a1x;
    R00 = a0x * u1x + a1x * u2x + w3x * u3x;
    R01 = a0x * u1y + a1x * u2y + w3x * u3y;
    R02 = a0x * u1z + a1x * u2z + w3x * u3z;
    R10 = a0y * u1x + a1y * u2x + w3y * u3x;
    R11 = a0y * u1y + a1y * u2y + w3y * u3y;
    R12 = a0y * u1z + a1y * u2z + w3y * u3z;
    R20 = a0z * u1x + a1z * u2x + w3z * u3x;
    R21 = a0z * u1y + a1z * u2y + w3z * u3y;
    R22 = a0z * u1z + a1z * u2z + w3z * u3z;
  }
  R9[0] = R00; R9[1] = R01; R9[2] = R02;
  R9[3] = R10; R9[4] = R11; R9[5] = R12;
  R9[6] = R20; R9[7] = R21; R9[8] = R22;
}

static __device__ __forceinline__ void heronCots(double A2, double B2, double C2,
                                                 double* c0, double* c1, double* c2) {
  double A = sqrt(A2), Bl = sqrt(B2), C = sqrt(C2);
  double s = 0.5 * (A + Bl + C);
  double pr = s * (s - A) * (s - Bl) * (s - C);
  pr = pr < 1e-12 ? 1e-12 : pr;
  double inv4 = 1.0 / (4.0 * sqrt(pr));
  *c0 = (B2 + C2 - A2) * inv4;
  *c1 = (A2 + C2 - B2) * inv4;
  *c2 = (A2 + B2 - C2) * inv4;
}

// Fused: per-(b,f) face prep (areas into cdf, scr cots, std cots) +
//        per-f adjacency fill + per-e std edge-length sum.
__global__ void kPrep(const float* vscr, const float* vstd, const int* faces,
                      const int* edges, double* cdf, double* ccot, double* scot,
                      int* adjcnt, int4* adjtab, double* accEdgeStd,
                      int B, int Vn, int F, int E) {
  int i = blockIdx.x * TPB + threadIdx.x;
  if (i < B * F) {
    int b = i / F, f = i % F;
    const float* vb = vscr + (size_t)b * Vn * 3;
    int i0 = faces[f * 3], i1 = faces[f * 3 + 1], i2 = faces[f * 3 + 2];
    {
      double p0x = vb[i0 * 3], p0y = vb[i0 * 3 + 1], p0z = vb[i0 * 3 + 2];
      double p1x = vb[i1 * 3], p1y = vb[i1 * 3 + 1], p1z = vb[i1 * 3 + 2];
      double p2x = vb[i2 * 3], p2y = vb[i2 * 3 + 1], p2z = vb[i2 * 3 + 2];
      double ax = p1x - p0x, ay = p1y - p0y, az = p1z - p0z;
      double bx = p2x - p0x, by = p2y - p0y, bz = p2z - p0z;
      double cx = ay * bz - az * by, cy = az * bx - ax * bz, cz = ax * by - ay * bx;
      cdf[i] = 0.5 * sqrt(cx * cx + cy * cy + cz * cz);
      double dx = p1x - p2x, dy = p1y - p2y, dz = p1z - p2z;
      double A2 = dx * dx + dy * dy + dz * dz;
      double B2 = bx * bx + by * by + bz * bz;
      double C2 = ax * ax + ay * ay + az * az;
      double c0, c1, c2;
      heronCots(A2, B2, C2, &c0, &c1, &c2);
      ccot[(size_t)i * 3 + 0] = c0;
      ccot[(size_t)i * 3 + 1] = c1;
      ccot[(size_t)i * 3 + 2] = c2;
    }
    if (b == 0) {
      double p0x = vstd[i0 * 3], p0y = vstd[i0 * 3 + 1], p0z = vstd[i0 * 3 + 2];
      double p1x = vstd[i1 * 3], p1y = vstd[i1 * 3 + 1], p1z = vstd[i1 * 3 + 2];
      double p2x = vstd[i2 * 3], p2y = vstd[i2 * 3 + 1], p2z = vstd[i2 * 3 + 2];
      double ax = p1x - p0x, ay = p1y - p0y, az = p1z - p0z;
      double bx = p2x - p0x, by = p2y - p0y, bz = p2z - p0z;
      double dx = p1x - p2x, dy = p1y - p2y, dz = p1z - p2z;
      double A2 = dx * dx + dy * dy + dz * dz;
      double B2 = bx * bx + by * by + bz * bz;
      double C2 = ax * ax + ay * ay + az * az;
      double c0, c1, c2;
      heronCots(A2, B2, C2, &c0, &c1, &c2);
      scot[(size_t)f * 3 + 0] = c0;
      scot[(size_t)f * 3 + 1] = c1;
      scot[(size_t)f * 3 + 2] = c2;
      // adjacency fill (faces are batch-invariant)
      int f3 = f * 3;
      int s0 = atomicAdd(&adjcnt[i0], 1);
      if (s0 < MAXDEG) adjtab[(size_t)i0 * MAXDEG + s0] = make_int4(i1, i2, f3 + 1, f3 + 2);
      int s1 = atomicAdd(&adjcnt[i1], 1);
      if (s1 < MAXDEG) adjtab[(size_t)i1 * MAXDEG + s1] = make_int4(i2, i0, f3 + 2, f3 + 0);
      int s2 = atomicAdd(&adjcnt[i2], 1);
      if (s2 < MAXDEG) adjtab[(size_t)i2 * MAXDEG + s2] = make_int4(i0, i1, f3 + 0, f3 + 1);
    }
  }
  double eval = 0.0;
  if (i < E) {
    int e0 = edges[(size_t)i * 2], e1 = edges[(size_t)i * 2 + 1];
    double dx = (double)vstd[e0 * 3 + 0] - vstd[e1 * 3 + 0];
    double dy = (double)vstd[e0 * 3 + 1] - vstd[e1 * 3 + 1];
    double dz = (double)vstd[e0 * 3 + 2] - vstd[e1 * 3 + 2];
    eval = sqrt(dx * dx + dy * dy + dz * dz);
  }
  double r = bredsum(eval);
  if (threadIdx.x == 0) atomAddD(accEdgeStd, r);
}

// Single-pass scan: per-chunk inclusive scan (wave shuffles) + chunk sums;
// last-finishing block computes per-batch exclusive chunk offsets.
__global__ void kScanFused(double* a, double* bsum, double* boffs, int F, int nc,
                           int B, int* cnt) {
  int blk = blockIdx.x;
  int b = blk / nc, c = blk % nc;
  int t = threadIdx.x, lane = t & 63, wid = t >> 6;
  int f = c * 1024 + t;
  size_t idx = (size_t)b * F + f;
  double v = (f < F) ? a[idx] : 0.0;
  double x = v;
#pragma unroll
  for (int o = 1; o < 64; o <<= 1) {
    double y = __shfl_up(x, o, 64);
    if (lane >= o) x += y;
  }
  __shared__ double wsum[16];
  __shared__ double woffs[16];
  if (lane == 63) wsum[wid] = x;
  __syncthreads();
  if (wid == 0) {
    double s = (lane < 16) ? wsum[lane] : 0.0;
    double xs = s;
#pragma unroll
    for (int o = 1; o < 16; o <<= 1) {
      double y = __shfl_up(xs, o, 64);
      if (lane >= o) xs += y;
    }
    double ex = __shfl_up(xs, 1, 64);
    if (lane < 16) woffs[lane] = (lane == 0) ? 0.0 : ex;
  }
  __syncthreads();
  x += woffs[wid];
  if (f < F) a[idx] = x;
  if (t == 1023) bsum[(size_t)b * nc + c] = x;
  // all stores drained to L2 (coherence point) by the waitcnt before this barrier
  __syncthreads();
  __shared__ int amlast;
  if (t == 0) {
    __threadfence();
    int old = __hip_atomic_fetch_add(cnt, 1, __ATOMIC_ACQ_REL, __HIP_MEMORY_SCOPE_AGENT);
    amlast = (old == (int)gridDim.x - 1) ? 1 : 0;
  }
  __syncthreads();
  if (amlast && wid == 0) {
    for (int bb = 0; bb < B; bb++) {
      double carry = 0.0;
      for (int base = 0; base < nc; base += 64) {
        int cc = base + lane;
        double s = (cc < nc) ? bsum[(size_t)bb * nc + cc] : 0.0;
        double xs = s;
#pragma unroll
        for (int o = 1; o < 64; o <<= 1) {
          double y = __shfl_up(xs, o, 64);
          if (lane >= o) xs += y;
        }
        double ex = __shfl_up(xs, 1, 64);
        double excl = (lane == 0) ? 0.0 : ex;
        if (cc < nc) boffs[(size_t)bb * nc + cc] = carry + excl;
        carry += __shfl(xs, 63, 64);
      }
    }
  }
}

// two-level binary search: chunk offsets (boffs/bsum), then in-chunk scan
__global__ void kSample(const float* verts, const int* faces, const double* cdf,
                        const double* bsum, const double* boffs,
                        const float* rfu, const float* rbary, float* samples,
                        int B, int Vn, int F, int S, int nc) {
  int i = blockIdx.x * blockDim.x + threadIdx.x;
  if (i >= B * S) return;
  int b = i / S;
  const double* bo = boffs + (size_t)b * nc;
  const double* bs = bsum + (size_t)b * nc;
  double total = bo[nc - 1] + bs[nc - 1];
  double tgt = (double)rfu[i] * total;
  int lo = 0, hi = nc;  // first chunk with inclusive prefix >= tgt
  while (lo < hi) {
    int m = (lo + hi) >> 1;
    if (bo[m] + bs[m] < tgt) lo = m + 1; else hi = m;
  }
  int c = lo < nc ? lo : nc - 1;
  double thr = tgt - bo[c];
  const double* cc = cdf + (size_t)b * F + (size_t)c * 1024;
  int lim = F - c * 1024; if (lim > 1024) lim = 1024;
  lo = 0; hi = lim;
  while (lo < hi) {
    int m = (lo + hi) >> 1;
    if (cc[m] < thr) lo = m + 1; else hi = m;
  }
  int j = lo < lim ? lo : lim - 1;
  int f = c * 1024 + j;
  const float* vb = verts + (size_t)b * Vn * 3;
  int i0 = faces[f * 3], i1 = faces[f * 3 + 1], i2 = faces[f * 3 + 2];
  float r0 = rbary[(size_t)i * 2], r1 = rbary[(size_t)i * 2 + 1];
  float su = sqrtf(r0);
  float w0 = 1.f - su, w1 = su * (1.f - r1), w2 = su * r1;
  samples[(size_t)i * 3 + 0] = w0 * vb[i0 * 3 + 0] + w1 * vb[i1 * 3 + 0] + w2 * vb[i2 * 3 + 0];
  samples[(size_t)i * 3 + 1] = w0 * vb[i0 * 3 + 1] + w1 * vb[i1 * 3 + 1] + w2 * vb[i2 * 3 + 1];
  samples[(size_t)i * 3 + 2] = w0 * vb[i0 * 3 + 2] + w1 * vb[i1 * 3 + 2] + w2 * vb[i2 * 3 + 2];
}

// both chamfer directions in one launch: z = dir*B + b
__global__ void kChamferBoth(const float* smp, const float* trg, unsigned* rowmin,
                             int B, int S) {
  int z = blockIdx.z;
  int dir = z / B, b = z % B;
  const float* X = dir ? trg : smp;
  const float* Y = dir ? smp : trg;
  int i = blockIdx.x * TPB + threadIdx.x;
  int j0 = blockIdx.y * TPB;
  int n = min(TPB, S - j0);
  __shared__ float4 sy[TPB];
  const float* Yb = Y + ((size_t)b * S + j0) * 3;
  if ((int)threadIdx.x < n) {
    int t = threadIdx.x;
    sy[t] = make_float4(Yb[t * 3], Yb[t * 3 + 1], Yb[t * 3 + 2], 0.f);
  }
  __syncthreads();
  if (i >= S) return;
  const float* Xb = X + (size_t)b * S * 3;
  float x0 = Xb[i * 3], x1 = Xb[i * 3 + 1], x2 = Xb[i * 3 + 2];
  float inf = __int_as_float(0x7f800000);
  float m0 = inf, m1 = inf, m2 = inf, m3 = inf;
  int k = 0;
  for (; k + 4 <= n; k += 4) {
    float4 y0 = sy[k], y1 = sy[k + 1], y2 = sy[k + 2], y3 = sy[k + 3];
    float a0 = x0 - y0.x, b0 = x1 - y0.y, c0 = x2 - y0.z;
    float a1 = x0 - y1.x, b1 = x1 - y1.y, c1 = x2 - y1.z;
    float a2 = x0 - y2.x, b2 = x1 - y2.y, c2 = x2 - y2.z;
    float a3 = x0 - y3.x, b3 = x1 - y3.y, c3 = x2 - y3.z;
    m0 = fminf(m0, a0 * a0 + b0 * b0 + c0 * c0);
    m1 = fminf(m1, a1 * a1 + b1 * b1 + c1 * c1);
    m2 = fminf(m2, a2 * a2 + b2 * b2 + c2 * c2);
    m3 = fminf(m3, a3 * a3 + b3 * b3 + c3 * c3);
  }
  for (; k < n; k++) {
    float4 y = sy[k];
    float a = x0 - y.x, bb = x1 - y.y, cc = x2 - y.z;
    m0 = fminf(m0, a * a + bb * bb + cc * cc);
  }
  float mn = fminf(fminf(m0, m1), fminf(m2, m3));
  atomicMin(&rowmin[((size_t)dir * B + b) * S + i], __float_as_uint(mn));
}

// fused: rowmin reduction + scr edge loss
__global__ void kMisc(const unsigned* rm, int nrm, const float* vscr, const int* edges,
                      int B, int Vn, int E, const double* tacc,
                      double* accCh, double* accEd) {
  int i = blockIdx.x * TPB + threadIdx.x;
  double v = 0.0;
  if (i < nrm) v = (double)__uint_as_float(rm[i]);
  double r = bredsum(v);
  if (threadIdx.x == 0) atomAddD(accCh, r);
  double tl = tacc[0] / (double)E;
  double val = 0.0;
  if (i < B * E) {
    int b = i / E, e = i % E;
    const float* vb = vscr + (size_t)b * Vn * 3;
    int e0 = edges[(size_t)e * 2], e1 = edges[(size_t)e * 2 + 1];
    double dx = (double)vb[e0 * 3 + 0] - vb[e1 * 3 + 0];
    double dy = (double)vb[e0 * 3 + 1] - vb[e1 * 3 + 1];
    double dz = (double)vb[e0 * 3 + 2] - vb[e1 * 3 + 2];
    double l = sqrt(dx * dx + dy * dy + dz * dz);
    double d = l - tl;
    val = d * d;
  }
  double r2 = bredsum(val);
  if (threadIdx.x == 0) atomAddD(accEd, r2);
}

// ---- per-vertex: Laplacian norm + ARAP S + Kabsch R + rigid residual via
//      vrig = Qc + Qs - 2 tr(R S)   (R orthogonal), + last-block finalize ----
__global__ void kVertexFin(const float* vstd, const float* vscr,
                           const int* cnt, const int4* adjtab, const double* scot,
                           const double* ccot, int B, int Vn, int F,
                           double* accum, int* done, float* out, int S, int E) {
  int idx = blockIdx.x * TPB + threadIdx.x;
  double vlap = 0.0, vrig = 0.0;
  if (idx < B * Vn) {
    int b = idx / Vn, v = idx % Vn;
    const float* cb = vscr + (size_t)b * Vn * 3;
    const double* ccb = ccot + (size_t)b * F * 3;
    double pasx = vstd[v * 3], pasy = vstd[v * 3 + 1], pasz = vstd[v * 3 + 2];
    double pacx = cb[v * 3], pacy = cb[v * 3 + 1], pacz = cb[v * 3 + 2];
    int n = cnt[v];
    if (n > MAXDEG) n = MAXDEG;
    const int4* at = adjtab + (size_t)v * MAXDEG;
    double S00 = 0, S01 = 0, S02 = 0, S10 = 0, S11 = 0, S12 = 0, S20 = 0, S21 = 0, S22 = 0;
    double Lx = 0, Ly = 0, Lz = 0, rw = 0, Qs = 0, Qc = 0;
    for (int k = 0; k < n; k++) {
      int4 e = at[k];
      int jb = e.x, jc = e.y;
      double cBs = scot[e.z], cCs = scot[e.w];
      double cBc = ccb[e.z], cCc = ccb[e.w];
      double pbsx = vstd[jb * 3], pbsy = vstd[jb * 3 + 1], pbsz = vstd[jb * 3 + 2];
      double pcsx = vstd[jc * 3], pcsy = vstd[jc * 3 + 1], pcsz = vstd[jc * 3 + 2];
      double pbcx = cb[jb * 3], pbcy = cb[jb * 3 + 1], pbcz = cb[jb * 3 + 2];
      double pccx = cb[jc * 3], pccy = cb[jc * 3 + 1], pccz = cb[jc * 3 + 2];
      Lx += cCc * pbcx + cBc * pccx;
      Ly += cCc * pbcy + cBc * pccy;
      Lz += cCc * pbcz + cBc * pccz;
      rw += cBc + cCc;
      double e1sx = pasx - pbsx, e1sy = pasy - pbsy, e1sz = pasz - pbsz;
      double e2sx = pasx - pcsx, e2sy = pasy - pcsy, e2sz = pasz - pcsz;
      double e1cx = pacx - pbcx, e1cy = pacy - pbcy, e1cz = pacz - pbcz;
      double e2cx = pacx - pccx, e2cy = pacy - pccy, e2cz = pacz - pccz;
      S00 += cCs * e1sx * e1cx + cBs * e2sx * e2cx;
      S01 += cCs * e1sx * e1cy + cBs * e2sx * e2cy;
      S02 += cCs * e1sx * e1cz + cBs * e2sx * e2cz;
      S10 += cCs * e1sy * e1cx + cBs * e2sy * e2cx;
      S11 += cCs * e1sy * e1cy + cBs * e2sy * e2cy;
      S12 += cCs * e1sy * e1cz + cBs * e2sy * e2cz;
      S20 += cCs * e1sz * e1cx + cBs * e2sz * e2cx;
      S21 += cCs * e1sz * e1cy + cBs * e2sz * e2cy;
      S22 += cCs * e1sz * e1cz + cBs * e2sz * e2cz;
      Qs += cCs * (e1sx * e1sx + e1sy * e1sy + e1sz * e1sz)
          + cBs * (e2sx * e2sx + e2sy * e2sy + e2sz * e2sz);
      Qc += cCs * (e1cx * e1cx + e1cy * e1cy + e1cz * e1cz)
          + cBs * (e2cx * e2cx + e2cy * e2cy + e2cz * e2cz);
    }
    double inv = (rw > 0.0) ? 1.0 / fmax(rw, 1e-12) : 0.0;
    double dx = Lx * inv - pacx, dy = Ly * inv - pacy, dz = Lz * inv - pacz;
    vlap = sqrt(dx * dx + dy * dy + dz * dz);
    double S[3][3] = {{S00, S01, S02}, {S10, S11, S12}, {S20, S21, S22}};
    double R9[9];
    kabschR(S, R9);
    double trRS = R9[0] * S00 + R9[1] * S10 + R9[2] * S20
                + R9[3] * S01 + R9[4] * S11 + R9[5] * S21
                + R9[6] * S02 + R9[7] * S12 + R9[8] * S22;
    vrig = Qc + Qs - 2.0 * trRS;
  }
  double r1 = bredsum(vlap);
  if (threadIdx.x == 0) atomAddD(accum + 1, r1);
  double r2 = bredsum(vrig);
  if (threadIdx.x == 0) atomAddD(accum + 4, r2);
  // finalize in last-finishing block (prior kernels' accum writes are
  // stream-ordered; this kernel's via release on the done counter)
  __shared__ int amlast;
  if (threadIdx.x == 0) {
    __threadfence();
    int old = __hip_atomic_fetch_add(done, 1, __ATOMIC_ACQ_REL, __HIP_MEMORY_SCOPE_AGENT);
    amlast = (old == (int)gridDim.x - 1) ? 1 : 0;
  }
  __syncthreads();
  if (amlast && threadIdx.x == 0) {
    double a0 = __hip_atomic_load(accum + 0, __ATOMIC_RELAXED, __HIP_MEMORY_SCOPE_AGENT);
    double a1 = __hip_atomic_load(accum + 1, __ATOMIC_RELAXED, __HIP_MEMORY_SCOPE_AGENT);
    double a3 = __hip_atomic_load(accum + 3, __ATOMIC_RELAXED, __HIP_MEMORY_SCOPE_AGENT);
    double a4 = __hip_atomic_load(accum + 4, __ATOMIC_RELAXED, __HIP_MEMORY_SCOPE_AGENT);
    out[0] = (float)(a0 / ((double)B * S));
    out[1] = 1e-5f;
    out[2] = (float)(a1 / ((double)B * Vn));
    out[3] = (float)(a3 / ((double)B * E));
    out[4] = (float)(a4 / ((double)B * Vn));
  }
}

extern "C" void kernel_launch(void* const* d_in, const int* in_sizes, int n_in,
                              void* d_out, int out_size, void* d_ws, size_t ws_size,
                              hipStream_t stream) {
  const float* vscr = (const float*)d_in[0];
  const float* vstd = (const float*)d_in[1];
  const float* trg  = (const float*)d_in[2];
  const float* rfu  = (const float*)d_in[3];
  const float* rby  = (const float*)d_in[4];
  const int* faces  = (const int*)d_in[5];
  const int* edges  = (const int*)d_in[6];
  float* out = (float*)d_out;

  int nVs = in_sizes[1];
  int Vn = nVs / 3;
  int B = in_sizes[0] / nVs;
  int S = in_sizes[3] / B;
  int F = in_sizes[5] / 3;
  int E = in_sizes[6] / 2;
  int nc = (F + 1023) / 1024;

  char* p = (char*)d_ws;
  auto alloc = [&](size_t bytes) -> void* {
    void* r = (void*)p;
    p += (bytes + 255) & ~(size_t)255;
    return r;
  };
  double* cdf   = (double*)alloc((size_t)B * F * sizeof(double));
  double* bsum  = (double*)alloc((size_t)B * nc * sizeof(double));
  double* boffs = (double*)alloc((size_t)B * nc * sizeof(double));
  double* scot  = (double*)alloc((size_t)F * 3 * sizeof(double));
  double* ccot  = (double*)alloc((size_t)B * F * 3 * sizeof(double));
  float* samples   = (float*)alloc((size_t)B * S * 3 * sizeof(float));
  unsigned* rowmin = (unsigned*)alloc((size_t)2 * B * S * sizeof(unsigned));
  int4* adjtab  = (int4*)alloc((size_t)Vn * MAXDEG * sizeof(int4));
  // zeroed region: adjcnt[Vn] | counters[8 ints] | accum[8 doubles]
  size_t zbytes = (size_t)Vn * sizeof(int) + 8 * sizeof(int) + 8 * sizeof(double);
  char* zbase   = (char*)alloc(zbytes);
  int* adjcnt   = (int*)zbase;
  int* cnts     = (int*)(zbase + (size_t)Vn * sizeof(int));  // [0]=scan, [1]=fin
  double* accum = (double*)(zbase + (size_t)Vn * sizeof(int) + 8 * sizeof(int));
  // accum: [0]=chamfer, [1]=lap, [2]=target_len, [3]=edge, [4]=rigid

  hipMemsetAsync(zbase, 0, zbytes, stream);
  int nrm = 2 * B * S;
  hipMemsetAsync(rowmin, 0xFF, (size_t)nrm * sizeof(unsigned), stream);

  int BF = B * F;
  kPrep<<<(BF + TPB - 1) / TPB, TPB, 0, stream>>>(vscr, vstd, faces, edges, cdf, ccot,
                                                  scot, adjcnt, adjtab, accum + 2,
                                                  B, Vn, F, E);
  kScanFused<<<B * nc, 1024, 0, stream>>>(cdf, bsum, boffs, F, nc, B, cnts + 0);
  kSample<<<(B * S + TPB - 1) / TPB, TPB, 0, stream>>>(vscr, faces, cdf, bsum, boffs,
                                                       rfu, rby, samples, B, Vn, F, S, nc);
  dim3 cg((S + TPB - 1) / TPB, (S + TPB - 1) / TPB, 2 * B);
  kChamferBoth<<<cg, TPB, 0, stream>>>(samples, trg, rowmin, B, S);
  int nmisc = nrm > B * E ? nrm : B * E;
  kMisc<<<(nmisc + TPB - 1) / TPB, TPB, 0, stream>>>(rowmin, nrm, vscr, edges, B, Vn, E,
                                                     accum + 2, accum + 0, accum + 3);
  kVertexFin<<<(B * Vn + TPB - 1) / TPB, TPB, 0, stream>>>(vstd, vscr, adjcnt, adjtab,
                                                           scot, ccot, B, Vn, F,
                                                           accum, cnts + 1, out, S, E);
}